// Round 15
// baseline (126.169 us; speedup 1.0000x reference)
//
#include <hip/hip_runtime.h>
#include <cstddef>
#include <math.h>

#define BD 8
#define TD 256
#define SD 256
#define HD 512
#define K2F 2.885390081777927f    // 2*log2(e): arg of exp2 for e^(2x)

#define EXP2(x) __builtin_amdgcn_exp2f(x)
#define RCP(x)  __builtin_amdgcn_rcpf(x)

typedef __attribute__((ext_vector_type(8))) _Float16 half8;
typedef __attribute__((ext_vector_type(4))) _Float16 half4;
typedef __attribute__((ext_vector_type(4))) float float4v;

// exp2 with arg clamped so E in [2^-80, 2^80]: products overflow to inf -> rcp -> 0,
// underflow to 0 -> r = 1; no inf*0 NaN path possible.
__device__ __forceinline__ float exp2_sat(float x) {
    return EXP2(fminf(fmaxf(x, -80.0f), 80.0f));
}

#define LSTR 40   // LDS row stride (halves) for proj staging

// ================= projK: proj (fp16 MFMA, fused convert), 1024 threads =================
// R4..R14-verified body. One 64x64 tile per block; x=bid&7 (XCD/batch pin).
// Epilogue writes BOTH encT[b][h][s] (attnK fallback) and encS[b][s][h] (attnF path).
__global__ __launch_bounds__(1024) void projK(
    const float* __restrict__ enc, const float* __restrict__ qry,
    const float* __restrict__ Wh,  const float* __restrict__ Ws,
    float* __restrict__ encT, float* __restrict__ encS, float* __restrict__ qryf)
{
    __shared__ float smem[2560];               // 10 KB: LA | LB

    const int bid = blockIdx.x;                // 0..511
    const int tid = threadIdx.x;               // 0..1023
    const int l  = tid & 63;
    const int w  = tid >> 6;                   // wave 0..15
    const int rf = l & 15;
    const int q  = l >> 4;

    _Float16* LA = (_Float16*)smem;            // 64*40 halves = 5120 B
    _Float16* LB = (_Float16*)(smem + 1280);   // +5120 B

    const int x  = bid & 7;                    // XCD / owning batch
    const int k  = bid >> 3;                   // 0..63
    const bool isq = k >= 32;
    const int kk = k & 31;                     // 0..31
    const int my = (isq ? 32 : 0) + x * 4 + (kk & 3);
    const int n0 = (kk >> 2) * 64;
    const int m0 = my * 64;                    // stacked row 0..4095

    const bool stagesA = (tid < 512);          // wave-uniform (waves 0-7 vs 8-15)
    const int srow = (tid >> 3) & 63;          // staging row 0..63
    const int scol = (tid & 7) * 4;            // staging col (floats)
    const float* Sbase = stagesA
        ? (isq ? qry + (size_t)(m0 - 2048 + srow) * HD
               : enc + (size_t)(m0 + srow) * HD) + scol
        : (isq ? Ws : Wh) + (size_t)(n0 + srow) * HD + scol;
    _Float16* Ldst = (stagesA ? LA : LB) + srow * LSTR + scol;

    const int mi = (w & 3) * 16;               // wave row-strip (4)
    const int ni = (w >> 2) * 16;              // wave col-strip (4)

    float4v acc = {0, 0, 0, 0};

    float4 a0 = *(const float4*)(Sbase);

    for (int ks = 0; ks < 16; ++ks) {
        if (ks) __syncthreads();
        {
            half4 ha;
            ha[0]=(_Float16)a0.x; ha[1]=(_Float16)a0.y; ha[2]=(_Float16)a0.z; ha[3]=(_Float16)a0.w;
            *(half4*)Ldst = ha;
        }
        __syncthreads();
        if (ks + 1 < 16) a0 = *(const float4*)(Sbase + (ks + 1) * 32);
        half8 ah = *(const half8*)&LA[(mi + rf) * LSTR + q * 8];
        half8 bh = *(const half8*)&LB[(ni + rf) * LSTR + q * 8];
        acc = __builtin_amdgcn_mfma_f32_16x16x32_f16(ah, bh, acc, 0, 0, 0);
    }

    // Epilogue (verified map: m-local = mi + q*4 + r, n-local = ni + rf).
    if (!isq) {
        const int b  = m0 >> 8;                // == x by construction
        const int sb = (m0 & 255) + mi + q * 4;
        const int h  = n0 + ni + rf;
        float e0 = exp2_sat(acc[0]*K2F), e1 = exp2_sat(acc[1]*K2F);
        float e2 = exp2_sat(acc[2]*K2F), e3 = exp2_sat(acc[3]*K2F);
        // encT[b][h][s..s+3] (fallback path)
        *(float4*)(encT + (size_t)b * HD * SD + (size_t)h * SD + sb) =
            make_float4(e0, e1, e2, e3);
        // encS[b][s][h] (natural layout, attnF path) — qryf-style scatter
        float* es = encS + ((size_t)b * SD + sb) * HD + h;
        es[0 * HD] = e0; es[1 * HD] = e1; es[2 * HD] = e2; es[3 * HD] = e3;
    } else {
        const int mrow = (m0 - 2048) + mi + q * 4;
        #pragma unroll
        for (int r = 0; r < 4; ++r)
            qryf[(size_t)(mrow + r) * HD + n0 + ni + rf] = exp2_sat(acc[r] * K2F);
    }
}

// ================= attnF: fused score + softmax + AV, t-QUAD blocks =================
// R14 lesson: the t-oct fused kernel spilled (qreg 64 + o 32 + misc > 128 VGPR budget).
// Quad variant halves per-thread state: qreg[2][4]=32, a[4], o[4]=16 -> peak ~70 VGPR.
// Grid 512 = (b = bid>>6, XCD-balanced) x (t-quad = bid&63). 1024 threads.
// Score: scoreS v3 loop (R13-verified) with 4 t; wave-sync LDS transpose (stride 5,
//   2-way conflicts = free). Softmax: attn3K body (R11-verified; masked ternary
//   discards unwritten ssc). AV: attn_fb-shape o[4] tail (proven) + s>=len skip
//   (weights beyond len are exactly 0 -> bitwise identical).
// LDS 32832 B: qls[2048] (dead after hoist; wq[1024] aliases) | red[5120] (dead after
//   score; avred[4096] aliases) | ssc[1040]. All aliases barrier-separated.
__global__ __launch_bounds__(1024, 1) void attnF(
    const float* __restrict__ enc, const float* __restrict__ encS,
    const float* __restrict__ qryf, const float* __restrict__ v,
    const int* __restrict__ lens, float* __restrict__ out)
{
    __shared__ float smem[8208];      // 32832 B

    float* qls   = smem;              // [t][j] 4*512, dead after qreg hoist
    float* wq    = smem;              // [s][4] weights (alias qls)
    float* red   = smem + 2048;       // per-wave [64][5] transpose bufs (16*320)
    float* avred = smem + 2048;       // [2][4][512] (alias red)
    float* ssc   = smem + 7168;       // [4][260] raw scores

    const int bid = blockIdx.x;       // 0..511
    const int tid = threadIdx.x;
    const int b   = bid >> 6;         // 0..7 (64 consecutive bids -> spread over XCDs)
    const int tq  = bid & 63;
    const int t0  = tq * 4;
    const int len = lens[b];
    const int l = tid & 63;
    const int w = tid >> 6;           // 0..15

    if (tid < 512) {   // stage E_q: qls[t][j], float4 vectorized (512 x 1 float4)
        const float* qf = qryf + ((size_t)b * TD + t0) * HD;
        const int i = tid * 4;        // 0..2044
        *(float4*)&qls[i] = *(const float4*)(qf + (i >> 9) * HD + (i & 511));
    }
    __syncthreads();

    // hoist q (invariant across this wave's s): 8 ds_read_b128, once
    float4 qreg[2][4];
    #pragma unroll
    for (int i = 0; i < 2; ++i)
        #pragma unroll
        for (int t = 0; t < 4; ++t)
            qreg[i][t] = *(const float4*)&qls[t * 512 + i * 256 + 4 * l];
    float4 vreg[2];
    #pragma unroll
    for (int i = 0; i < 2; ++i)
        vreg[i] = *(const float4*)(v + i * 256 + 4 * l);

    const int tsel = l & 3;           // lane's t for transpose-read
    const int ck   = l >> 2;          // lane's row-chunk 0..15
    float* rb = red + w * 320;        // this wave's [64][5] buffer

    // ---- score phase: wave w covers s = k*16 + w, k ascending -> uniform break ----
    for (int k = 0; k < 16; ++k) {
        const int s = k * 16 + w;     // wave-uniform
        if (s >= len) break;

        const float* eb = encS + ((size_t)b * SD + s) * HD;
        float a[4];
        #pragma unroll
        for (int t = 0; t < 4; ++t) a[t] = 0.0f;

        #pragma unroll
        for (int i = 0; i < 2; ++i) {
            float4 e4 = *(const float4*)(eb + i * 256 + 4 * l);  // coalesced 1 KB/wave
            float4 v4 = vreg[i];
            #pragma unroll
            for (int t = 0; t < 4; ++t) {
                float4 q4 = qreg[i][t];
                float p;
                p = fmaf(e4.x, q4.x, 1.0f); a[t] = fmaf(v4.x, RCP(p), a[t]);
                p = fmaf(e4.y, q4.y, 1.0f); a[t] = fmaf(v4.y, RCP(p), a[t]);
                p = fmaf(e4.z, q4.z, 1.0f); a[t] = fmaf(v4.z, RCP(p), a[t]);
                p = fmaf(e4.w, q4.w, 1.0f); a[t] = fmaf(v4.w, RCP(p), a[t]);
            }
        }

        // wave-synchronous LDS transpose reduce (R13-verified pattern; stride 5)
        *(float4*)&rb[l * 5] = make_float4(a[0], a[1], a[2], a[3]);
        float part = 0.0f;
        #pragma unroll
        for (int i = 0; i < 4; ++i)
            part += rb[(ck * 4 + i) * 5 + tsel];
        part += __shfl_xor(part, 4);
        part += __shfl_xor(part, 8);
        part += __shfl_xor(part, 16);
        part += __shfl_xor(part, 32);
        if (l < 4)
            ssc[l * 260 + s] = part;   // raw score for (t=l, s)
    }
    __syncthreads();

    // ---- softmax: wave w<4 handles t=w; lane owns 4 s  [attn3K body, verified] ----
    if (w < 4) {
        const int t = w;
        const int s0 = l * 4;
        float p[4];
        #pragma unroll
        for (int c = 0; c < 4; ++c) p[c] = ssc[t * 260 + s0 + c];
        float sc[4];
        #pragma unroll
        for (int c = 0; c < 4; ++c)
            sc[c] = (s0 + c < len) ? -2.0f * p[c] : -INFINITY;
        float mx = fmaxf(fmaxf(sc[0], sc[1]), fmaxf(sc[2], sc[3]));
        #pragma unroll
        for (int off = 32; off; off >>= 1) mx = fmaxf(mx, __shfl_xor(mx, off));
        float ex[4]; float sum = 0.0f;
        #pragma unroll
        for (int c = 0; c < 4; ++c) { ex[c] = __expf(sc[c] - mx); sum += ex[c]; }
        #pragma unroll
        for (int off = 32; off; off >>= 1) sum += __shfl_xor(sum, off);
        const float inv = RCP(sum);
        #pragma unroll
        for (int c = 0; c < 4; ++c)
            wq[(s0 + c) * 4 + t] = ex[c] * inv;   // [s][4] layout: 1 float4 per AV s
    }
    __syncthreads();

    // ---- AV: attn_fb-shape tail (proven) + s>=len skip; wq read as 1 ds_read_b128 ----
    const int sg = tid >> 7;          // 0..7 (wave-pair-uniform)
    const int h4 = (tid & 127) * 4;
    float4 o[4];
    #pragma unroll
    for (int t = 0; t < 4; ++t) o[t] = make_float4(0.f, 0.f, 0.f, 0.f);
    {
        const float* eb = enc + (size_t)b * SD * HD + h4;
        #pragma unroll 2
        for (int ss = 0; ss < 32; ++ss) {
            const int s = sg * 32 + ss;          // wave-uniform
            if (s >= len) break;                 // weights beyond len are exactly 0
            float4 evv = *(const float4*)(eb + (size_t)s * HD);
            float4 w4 = *(const float4*)&wq[s * 4];   // t=0..3 (broadcast)
            float wt[4] = {w4.x, w4.y, w4.z, w4.w};
            #pragma unroll
            for (int t = 0; t < 4; ++t) {
                o[t].x = fmaf(wt[t], evv.x, o[t].x);
                o[t].y = fmaf(wt[t], evv.y, o[t].y);
                o[t].z = fmaf(wt[t], evv.z, o[t].z);
                o[t].w = fmaf(wt[t], evv.w, o[t].w);
            }
        }
    }
    __syncthreads();   // red region dead; safe to write avred

    // 2-slot reduce in 4 stages (attnK pattern, o[4])
    if (sg < 2) {
        #pragma unroll
        for (int t = 0; t < 4; ++t)
            *(float4*)&avred[(size_t)(sg * 4 + t) * 512 + h4] = o[t];
    }
    __syncthreads();
    if (sg >= 2 && sg < 4) {
        #pragma unroll
        for (int t = 0; t < 4; ++t) {
            float4 c4 = *(const float4*)&avred[(size_t)((sg - 2) * 4 + t) * 512 + h4];
            c4.x += o[t].x; c4.y += o[t].y; c4.z += o[t].z; c4.w += o[t].w;
            *(float4*)&avred[(size_t)((sg - 2) * 4 + t) * 512 + h4] = c4;
        }
    }
    __syncthreads();
    if (sg >= 4 && sg < 6) {
        #pragma unroll
        for (int t = 0; t < 4; ++t) {
            float4 c4 = *(const float4*)&avred[(size_t)((sg - 4) * 4 + t) * 512 + h4];
            c4.x += o[t].x; c4.y += o[t].y; c4.z += o[t].z; c4.w += o[t].w;
            *(float4*)&avred[(size_t)((sg - 4) * 4 + t) * 512 + h4] = c4;
        }
    }
    __syncthreads();
    if (sg >= 6) {
        #pragma unroll
        for (int t = 0; t < 4; ++t) {
            float4 c4 = *(const float4*)&avred[(size_t)((sg - 6) * 4 + t) * 512 + h4];
            c4.x += o[t].x; c4.y += o[t].y; c4.z += o[t].z; c4.w += o[t].w;
            *(float4*)&avred[(size_t)((sg - 6) * 4 + t) * 512 + h4] = c4;
        }
    }
    __syncthreads();

    if (tid < 512) {
        const int t  = tid >> 7;      // 0..3
        const int hh = (tid & 127) * 4;
        float4 x0 = *(const float4*)&avred[(size_t)(0 * 4 + t) * 512 + hh];
        float4 x1 = *(const float4*)&avred[(size_t)(1 * 4 + t) * 512 + hh];
        float4 r = make_float4(x0.x + x1.x, x0.y + x1.y, x0.z + x1.z, x0.w + x1.w);
        *(float4*)(out + ((size_t)b * TD + t0 + t) * HD + hh) = r;
    }
}

// ================= attnK: R7/R9-proven fused attn (fallback; bench 117.8) =================
__global__ __launch_bounds__(1024) void attnK(
    const float* __restrict__ enc, const float* __restrict__ encT,
    const float* __restrict__ qryf, const float* __restrict__ v,
    const int* __restrict__ lens, float* __restrict__ out)
{
    __shared__ float smem[14336];    // 56 KB

    const int bid = blockIdx.x;      // 0..255
    const int tid = threadIdx.x;
    const int b   = bid & 7;
    const int t0  = (bid >> 3) * 8;
    const int l = tid & 63;
    const int w = tid >> 6;          // 0..15

    float* qls = smem;               // [t][j] 8*512 floats
    float* pls = smem + 4096;        // [4][8][256] floats; aliased avred
    float* wls = smem + 12288;       // [8][256] floats

    {
        const float* qf = qryf + ((size_t)b * TD + t0) * HD;
        const int j = tid & 511;
        #pragma unroll
        for (int t = (tid >> 9); t < 8; t += 2)
            qls[t * 512 + j] = qf[t * HD + j];
    }
    __syncthreads();

    float a[8][4];
    #pragma unroll
    for (int t = 0; t < 8; ++t)
        #pragma unroll
        for (int c = 0; c < 4; ++c) a[t][c] = 0.0f;
    {
        const int jbase = w * 32;
        const float* ep = encT + (size_t)b * HD * SD + (size_t)jbase * SD + l * 4;
        #pragma unroll 4
        for (int jj = 0; jj < 32; ++jj) {
            float4 e = *(const float4*)(ep + (size_t)jj * SD);
            float vj = v[jbase + jj];
            float qv[8];
            #pragma unroll
            for (int t = 0; t < 8; ++t) qv[t] = qls[t * 512 + jbase + jj];
            float ev[4] = {e.x, e.y, e.z, e.w};
            #pragma unroll
            for (int t = 0; t < 8; ++t)
                #pragma unroll
                for (int c = 0; c < 4; ++c) {
                    float p = fmaf(ev[c], qv[t], 1.0f);
                    a[t][c] = fmaf(vj, RCP(p), a[t][c]);
                }
        }
    }
    if (w < 4) {
        #pragma unroll
        for (int t = 0; t < 8; ++t)
            *(float4*)&pls[(w * 8 + t) * 256 + l * 4] =
                make_float4(a[t][0], a[t][1], a[t][2], a[t][3]);
    }
    __syncthreads();
    if (w >= 4 && w < 8) {
        #pragma unroll
        for (int t = 0; t < 8; ++t) {
            float4 c4 = *(const float4*)&pls[((w - 4) * 8 + t) * 256 + l * 4];
            c4.x += a[t][0]; c4.y += a[t][1]; c4.z += a[t][2]; c4.w += a[t][3];
            *(float4*)&pls[((w - 4) * 8 + t) * 256 + l * 4] = c4;
        }
    }
    __syncthreads();
    if (w >= 8 && w < 12) {
        #pragma unroll
        for (int t = 0; t < 8; ++t) {
            float4 c4 = *(const float4*)&pls[((w - 8) * 8 + t) * 256 + l * 4];
            c4.x += a[t][0]; c4.y += a[t][1]; c4.z += a[t][2]; c4.w += a[t][3];
            *(float4*)&pls[((w - 8) * 8 + t) * 256 + l * 4] = c4;
        }
    }
    __syncthreads();
    if (w >= 12) {
        #pragma unroll
        for (int t = 0; t < 8; ++t) {
            float4 c4 = *(const float4*)&pls[((w - 12) * 8 + t) * 256 + l * 4];
            c4.x += a[t][0]; c4.y += a[t][1]; c4.z += a[t][2]; c4.w += a[t][3];
            *(float4*)&pls[((w - 12) * 8 + t) * 256 + l * 4] = c4;
        }
    }
    __syncthreads();

    if (w < 8) {
        const int t = w;
        float p[4] = {0, 0, 0, 0};
        #pragma unroll
        for (int g = 0; g < 4; ++g) {
            float4 pp = *(const float4*)&pls[(g * 8 + t) * 256 + l * 4];
            p[0] += pp.x; p[1] += pp.y; p[2] += pp.z; p[3] += pp.w;
        }
        const int len = lens[b];
        const int s0 = l * 4;
        float sc[4];
        #pragma unroll
        for (int c = 0; c < 4; ++c)
            sc[c] = (s0 + c < len) ? -2.0f * p[c] : -INFINITY;
        float mx = fmaxf(fmaxf(sc[0], sc[1]), fmaxf(sc[2], sc[3]));
        #pragma unroll
        for (int off = 32; off; off >>= 1) mx = fmaxf(mx, __shfl_xor(mx, off));
        float ex[4]; float sum = 0.0f;
        #pragma unroll
        for (int c = 0; c < 4; ++c) { ex[c] = __expf(sc[c] - mx); sum += ex[c]; }
        #pragma unroll
        for (int off = 32; off; off >>= 1) sum += __shfl_xor(sum, off);
        const float inv = RCP(sum);
        *(float4*)&wls[t * SD + s0] = make_float4(ex[0]*inv, ex[1]*inv, ex[2]*inv, ex[3]*inv);
    }
    __syncthreads();

    const int sg = tid >> 7;
    const int h4 = (tid & 127) * 4;
    float* avred = pls;
    float4 o[8];
    #pragma unroll
    for (int t = 0; t < 8; ++t) o[t] = make_float4(0.f, 0.f, 0.f, 0.f);
    {
        const float* eb = enc + (size_t)b * SD * HD + h4;
        #pragma unroll 2
        for (int ss = 0; ss < 32; ++ss) {
            const int s = sg * 32 + ss;
            float4 evv = *(const float4*)(eb + (size_t)s * HD);
            float wt[8];
            #pragma unroll
            for (int t = 0; t < 8; ++t) wt[t] = wls[t * SD + s];
            #pragma unroll
            for (int t = 0; t < 8; ++t) {
                o[t].x = fmaf(wt[t], evv.x, o[t].x);
                o[t].y = fmaf(wt[t], evv.y, o[t].y);
                o[t].z = fmaf(wt[t], evv.z, o[t].z);
                o[t].w = fmaf(wt[t], evv.w, o[t].w);
            }
        }
    }
    if (sg < 2) {
        #pragma unroll
        for (int t = 0; t < 8; ++t)
            *(float4*)&avred[(size_t)(sg * 8 + t) * 512 + h4] = o[t];
    }
    __syncthreads();
    if (sg >= 2 && sg < 4) {
        #pragma unroll
        for (int t = 0; t < 8; ++t) {
            float4 c4 = *(const float4*)&avred[(size_t)((sg - 2) * 8 + t) * 512 + h4];
            c4.x += o[t].x; c4.y += o[t].y; c4.z += o[t].z; c4.w += o[t].w;
            *(float4*)&avred[(size_t)((sg - 2) * 8 + t) * 512 + h4] = c4;
        }
    }
    __syncthreads();
    if (sg >= 4 && sg < 6) {
        #pragma unroll
        for (int t = 0; t < 8; ++t) {
            float4 c4 = *(const float4*)&avred[(size_t)((sg - 4) * 8 + t) * 512 + h4];
            c4.x += o[t].x; c4.y += o[t].y; c4.z += o[t].z; c4.w += o[t].w;
            *(float4*)&avred[(size_t)((sg - 4) * 8 + t) * 512 + h4] = c4;
        }
    }
    __syncthreads();
    if (sg >= 6) {
        #pragma unroll
        for (int t = 0; t < 8; ++t) {
            float4 c4 = *(const float4*)&avred[(size_t)((sg - 6) * 8 + t) * 512 + h4];
            c4.x += o[t].x; c4.y += o[t].y; c4.z += o[t].z; c4.w += o[t].w;
            *(float4*)&avred[(size_t)((sg - 6) * 8 + t) * 512 + h4] = c4;
        }
    }
    __syncthreads();

    {
        const int t  = tid >> 7;
        const int hh = (tid & 127) * 4;
        float4 x0 = *(const float4*)&avred[(size_t)(0 * 8 + t) * 512 + hh];
        float4 x1 = *(const float4*)&avred[(size_t)(1 * 8 + t) * 512 + hh];
        float4 r = make_float4(x0.x + x1.x, x0.y + x1.y, x0.z + x1.z, x0.w + x1.w);
        *(float4*)(out + ((size_t)b * TD + t0 + t) * HD + hh) = r;
    }
}

extern "C" void kernel_launch(void* const* d_in, const int* in_sizes, int n_in,
                              void* d_out, int out_size, void* d_ws, size_t ws_size,
                              hipStream_t stream) {
    const float* query = (const float*)d_in[0];
    const float* enc   = (const float*)d_in[1];
    const int*   lens  = (const int*)d_in[2];
    const float* W_h   = (const float*)d_in[3];
    const float* W_s   = (const float*)d_in[4];
    const float* v     = (const float*)d_in[5];
    float* out = (float*)d_out;

    char* ws = (char*)d_ws;
    float* encT  = (float*)(ws);                       // 4 MB (B,H,S)  E_e transposed
    float* qryf  = (float*)(ws + ((size_t)4 << 20));   // 4 MB (B,T,H)  E_q
    float* encS  = (float*)(ws + ((size_t)8 << 20));   // 4 MB (B,S,H)  E_e natural

    // Plain launches only — graph-capture-safe (R7 lesson).
    projK<<<dim3(512), dim3(1024), 0, stream>>>(enc, query, W_h, W_s, encT, encS, qryf);

    // Spill guard (R8 lesson): only the catastrophe gates.
    bool use_f = (ws_size >= ((size_t)12 << 20));
    hipFuncAttributes fa{};
    if (use_f &&
        hipFuncGetAttributes(&fa, (const void*)attnF) == hipSuccess &&
        fa.localSizeBytes > 0) {
        use_f = false;
    }

    if (use_f) {
        // fused score+softmax+AV (t-quad, ~70 VGPR), lens-skip in score AND AV.
        attnF<<<dim3(512), dim3(1024), 0, stream>>>(enc, encS, qryf, v, lens, out);
    } else {
        // R7/R9-proven fused attn (bench 117.8 us).
        attnK<<<dim3(256), dim3(1024), 0, stream>>>(enc, encT, qryf, v, lens, out);
    }
}

// Round 16
// 118.272 us; speedup vs baseline: 1.0668x; 1.0668x over previous
//
#include <hip/hip_runtime.h>
#include <cstddef>
#include <math.h>

#define BD 8
#define TD 256
#define SD 256
#define HD 512
#define K2F 2.885390081777927f    // 2*log2(e): arg of exp2 for e^(2x)

#define EXP2(x) __builtin_amdgcn_exp2f(x)
#define RCP(x)  __builtin_amdgcn_rcpf(x)

typedef __attribute__((ext_vector_type(8))) _Float16 half8;
typedef __attribute__((ext_vector_type(4))) _Float16 half4;
typedef __attribute__((ext_vector_type(4))) float float4v;

// exp2 with arg clamped so E in [2^-80, 2^80]: products overflow to inf -> rcp -> 0,
// underflow to 0 -> r = 1; no inf*0 NaN path possible.
__device__ __forceinline__ float exp2_sat(float x) {
    return EXP2(fminf(fmaxf(x, -80.0f), 80.0f));
}

#define LSTR 40   // LDS row stride (halves) for proj staging

// ================= projK: proj (fp16 MFMA, fused convert), 1024 threads =================
// R7-proven body (absmax-verified every round since R4). One 64x64 tile per block;
// x=bid&7 (XCD/batch pin), k=bid>>3. Threads 0-511 stage A, 512-1023 stage B.
__global__ __launch_bounds__(1024) void projK(
    const float* __restrict__ enc, const float* __restrict__ qry,
    const float* __restrict__ Wh,  const float* __restrict__ Ws,
    float* __restrict__ encT, float* __restrict__ qryf)
{
    __shared__ float smem[2560];               // 10 KB: LA | LB

    const int bid = blockIdx.x;                // 0..511
    const int tid = threadIdx.x;               // 0..1023
    const int l  = tid & 63;
    const int w  = tid >> 6;                   // wave 0..15
    const int rf = l & 15;
    const int q  = l >> 4;

    _Float16* LA = (_Float16*)smem;            // 64*40 halves = 5120 B
    _Float16* LB = (_Float16*)(smem + 1280);   // +5120 B

    const int x  = bid & 7;                    // XCD / owning batch
    const int k  = bid >> 3;                   // 0..63
    const bool isq = k >= 32;
    const int kk = k & 31;                     // 0..31
    const int my = (isq ? 32 : 0) + x * 4 + (kk & 3);
    const int n0 = (kk >> 2) * 64;
    const int m0 = my * 64;                    // stacked row 0..4095

    const bool stagesA = (tid < 512);          // wave-uniform (waves 0-7 vs 8-15)
    const int srow = (tid >> 3) & 63;          // staging row 0..63
    const int scol = (tid & 7) * 4;            // staging col (floats)
    const float* Sbase = stagesA
        ? (isq ? qry + (size_t)(m0 - 2048 + srow) * HD
               : enc + (size_t)(m0 + srow) * HD) + scol
        : (isq ? Ws : Wh) + (size_t)(n0 + srow) * HD + scol;
    _Float16* Ldst = (stagesA ? LA : LB) + srow * LSTR + scol;

    const int mi = (w & 3) * 16;               // wave row-strip (4)
    const int ni = (w >> 2) * 16;              // wave col-strip (4)

    float4v acc = {0, 0, 0, 0};

    float4 a0 = *(const float4*)(Sbase);

    for (int ks = 0; ks < 16; ++ks) {
        if (ks) __syncthreads();
        {
            half4 ha;
            ha[0]=(_Float16)a0.x; ha[1]=(_Float16)a0.y; ha[2]=(_Float16)a0.z; ha[3]=(_Float16)a0.w;
            *(half4*)Ldst = ha;
        }
        __syncthreads();
        if (ks + 1 < 16) a0 = *(const float4*)(Sbase + (ks + 1) * 32);
        half8 ah = *(const half8*)&LA[(mi + rf) * LSTR + q * 8];
        half8 bh = *(const half8*)&LB[(ni + rf) * LSTR + q * 8];
        acc = __builtin_amdgcn_mfma_f32_16x16x32_f16(ah, bh, acc, 0, 0, 0);
    }

    // Epilogue (verified map: m-local = mi + q*4 + r, n-local = ni + rf).
    if (!isq) {
        const int b  = m0 >> 8;                // == x by construction
        const int sb = (m0 & 255) + mi + q * 4;
        float* base = encT + (size_t)b * HD * SD;
        float4 o = make_float4(exp2_sat(acc[0]*K2F), exp2_sat(acc[1]*K2F),
                               exp2_sat(acc[2]*K2F), exp2_sat(acc[3]*K2F));
        *(float4*)(base + (size_t)(n0 + ni + rf) * SD + sb) = o;
    } else {
        const int mrow = (m0 - 2048) + mi + q * 4;
        #pragma unroll
        for (int r = 0; r < 4; ++r)
            qryf[(size_t)(mrow + r) * HD + n0 + ni + rf] = exp2_sat(acc[r] * K2F);
    }
}

// ================= attnK2: attnK + 8-deep score-loop prefetch, 128-VGPR budget ==========
// R6's MLP experiment, finally with the register budget sized for it: body 52 VGPR
// (R7-measured) + e8[8] batch 32 ~= 84-95 < 128 ( __launch_bounds__(1024,1) — form
// validated by R15's attnF: 56 VGPR, no spill, under the same bounds).
// Score-loop update order (jj ascending) identical to attnK -> bitwise-identical out.
// All other phases verbatim attnK (R7/R9-proven). Cost: 4 waves/SIMD (R5: wave count
// is not the constraint); gain: 8 loads in flight/wave = 128 KB/CU outstanding.
__global__ __launch_bounds__(1024, 1) void attnK2(
    const float* __restrict__ enc, const float* __restrict__ encT,
    const float* __restrict__ qryf, const float* __restrict__ v,
    const int* __restrict__ lens, float* __restrict__ out)
{
    __shared__ float smem[14336];    // 56 KB

    const int bid = blockIdx.x;      // 0..255
    const int tid = threadIdx.x;
    const int b   = bid & 7;
    const int t0  = (bid >> 3) * 8;
    const int l = tid & 63;
    const int w = tid >> 6;          // 0..15

    float* qls = smem;               // [t][j] 8*512 floats
    float* pls = smem + 4096;        // [4][8][256] floats; aliased avred
    float* wls = smem + 12288;       // [8][256] floats

    {
        const float* qf = qryf + ((size_t)b * TD + t0) * HD;
        const int j = tid & 511;
        #pragma unroll
        for (int t = (tid >> 9); t < 8; t += 2)
            qls[t * 512 + j] = qf[t * HD + j];
    }
    __syncthreads();

    float a[8][4];
    #pragma unroll
    for (int t = 0; t < 8; ++t)
        #pragma unroll
        for (int c = 0; c < 4; ++c) a[t][c] = 0.0f;
    {
        const int jbase = w * 32;
        const float* ep = encT + (size_t)b * HD * SD + (size_t)jbase * SD + l * 4;
        #pragma unroll 1
        for (int j0 = 0; j0 < 32; j0 += 8) {
            float4 e8[8];                        // 8 independent rows in flight
            #pragma unroll
            for (int u = 0; u < 8; ++u)
                e8[u] = *(const float4*)(ep + (size_t)(j0 + u) * SD);
            #pragma unroll
            for (int u = 0; u < 8; ++u) {
                const int jj = j0 + u;
                const float vj = v[jbase + jj];
                float qv[8];
                #pragma unroll
                for (int t = 0; t < 8; ++t) qv[t] = qls[t * 512 + jbase + jj];
                float ev[4] = {e8[u].x, e8[u].y, e8[u].z, e8[u].w};
                #pragma unroll
                for (int t = 0; t < 8; ++t)
                    #pragma unroll
                    for (int c = 0; c < 4; ++c) {
                        float p = fmaf(ev[c], qv[t], 1.0f);
                        a[t][c] = fmaf(vj, RCP(p), a[t][c]);
                    }
            }
        }
    }
    if (w < 4) {
        #pragma unroll
        for (int t = 0; t < 8; ++t)
            *(float4*)&pls[(w * 8 + t) * 256 + l * 4] =
                make_float4(a[t][0], a[t][1], a[t][2], a[t][3]);
    }
    __syncthreads();
    if (w >= 4 && w < 8) {
        #pragma unroll
        for (int t = 0; t < 8; ++t) {
            float4 c4 = *(const float4*)&pls[((w - 4) * 8 + t) * 256 + l * 4];
            c4.x += a[t][0]; c4.y += a[t][1]; c4.z += a[t][2]; c4.w += a[t][3];
            *(float4*)&pls[((w - 4) * 8 + t) * 256 + l * 4] = c4;
        }
    }
    __syncthreads();
    if (w >= 8 && w < 12) {
        #pragma unroll
        for (int t = 0; t < 8; ++t) {
            float4 c4 = *(const float4*)&pls[((w - 8) * 8 + t) * 256 + l * 4];
            c4.x += a[t][0]; c4.y += a[t][1]; c4.z += a[t][2]; c4.w += a[t][3];
            *(float4*)&pls[((w - 8) * 8 + t) * 256 + l * 4] = c4;
        }
    }
    __syncthreads();
    if (w >= 12) {
        #pragma unroll
        for (int t = 0; t < 8; ++t) {
            float4 c4 = *(const float4*)&pls[((w - 12) * 8 + t) * 256 + l * 4];
            c4.x += a[t][0]; c4.y += a[t][1]; c4.z += a[t][2]; c4.w += a[t][3];
            *(float4*)&pls[((w - 12) * 8 + t) * 256 + l * 4] = c4;
        }
    }
    __syncthreads();

    if (w < 8) {
        const int t = w;
        float p[4] = {0, 0, 0, 0};
        #pragma unroll
        for (int g = 0; g < 4; ++g) {
            float4 pp = *(const float4*)&pls[(g * 8 + t) * 256 + l * 4];
            p[0] += pp.x; p[1] += pp.y; p[2] += pp.z; p[3] += pp.w;
        }
        const int len = lens[b];
        const int s0 = l * 4;
        float sc[4];
        #pragma unroll
        for (int c = 0; c < 4; ++c)
            sc[c] = (s0 + c < len) ? -2.0f * p[c] : -INFINITY;
        float mx = fmaxf(fmaxf(sc[0], sc[1]), fmaxf(sc[2], sc[3]));
        #pragma unroll
        for (int off = 32; off; off >>= 1) mx = fmaxf(mx, __shfl_xor(mx, off));
        float ex[4]; float sum = 0.0f;
        #pragma unroll
        for (int c = 0; c < 4; ++c) { ex[c] = __expf(sc[c] - mx); sum += ex[c]; }
        #pragma unroll
        for (int off = 32; off; off >>= 1) sum += __shfl_xor(sum, off);
        const float inv = RCP(sum);
        *(float4*)&wls[t * SD + s0] = make_float4(ex[0]*inv, ex[1]*inv, ex[2]*inv, ex[3]*inv);
    }
    __syncthreads();

    const int sg = tid >> 7;
    const int h4 = (tid & 127) * 4;
    float* avred = pls;
    float4 o[8];
    #pragma unroll
    for (int t = 0; t < 8; ++t) o[t] = make_float4(0.f, 0.f, 0.f, 0.f);
    {
        const float* eb = enc + (size_t)b * SD * HD + h4;
        #pragma unroll 2
        for (int ss = 0; ss < 32; ++ss) {
            const int s = sg * 32 + ss;
            float4 evv = *(const float4*)(eb + (size_t)s * HD);
            float wt[8];
            #pragma unroll
            for (int t = 0; t < 8; ++t) wt[t] = wls[t * SD + s];
            #pragma unroll
            for (int t = 0; t < 8; ++t) {
                o[t].x = fmaf(wt[t], evv.x, o[t].x);
                o[t].y = fmaf(wt[t], evv.y, o[t].y);
                o[t].z = fmaf(wt[t], evv.z, o[t].z);
                o[t].w = fmaf(wt[t], evv.w, o[t].w);
            }
        }
    }
    if (sg < 2) {
        #pragma unroll
        for (int t = 0; t < 8; ++t)
            *(float4*)&avred[(size_t)(sg * 8 + t) * 512 + h4] = o[t];
    }
    __syncthreads();
    if (sg >= 2 && sg < 4) {
        #pragma unroll
        for (int t = 0; t < 8; ++t) {
            float4 c4 = *(const float4*)&avred[(size_t)((sg - 2) * 8 + t) * 512 + h4];
            c4.x += o[t].x; c4.y += o[t].y; c4.z += o[t].z; c4.w += o[t].w;
            *(float4*)&avred[(size_t)((sg - 2) * 8 + t) * 512 + h4] = c4;
        }
    }
    __syncthreads();
    if (sg >= 4 && sg < 6) {
        #pragma unroll
        for (int t = 0; t < 8; ++t) {
            float4 c4 = *(const float4*)&avred[(size_t)((sg - 4) * 8 + t) * 512 + h4];
            c4.x += o[t].x; c4.y += o[t].y; c4.z += o[t].z; c4.w += o[t].w;
            *(float4*)&avred[(size_t)((sg - 4) * 8 + t) * 512 + h4] = c4;
        }
    }
    __syncthreads();
    if (sg >= 6) {
        #pragma unroll
        for (int t = 0; t < 8; ++t) {
            float4 c4 = *(const float4*)&avred[(size_t)((sg - 6) * 8 + t) * 512 + h4];
            c4.x += o[t].x; c4.y += o[t].y; c4.z += o[t].z; c4.w += o[t].w;
            *(float4*)&avred[(size_t)((sg - 6) * 8 + t) * 512 + h4] = c4;
        }
    }
    __syncthreads();

    {
        const int t  = tid >> 7;
        const int hh = (tid & 127) * 4;
        float4 x0 = *(const float4*)&avred[(size_t)(0 * 8 + t) * 512 + hh];
        float4 x1 = *(const float4*)&avred[(size_t)(1 * 8 + t) * 512 + hh];
        float4 r = make_float4(x0.x + x1.x, x0.y + x1.y, x0.z + x1.z, x0.w + x1.w);
        *(float4*)(out + ((size_t)b * TD + t0 + t) * HD + hh) = r;
    }
}

// ================= attnK: R7/R9-proven fused attn (fallback; bench 117.8) =================
__global__ __launch_bounds__(1024) void attnK(
    const float* __restrict__ enc, const float* __restrict__ encT,
    const float* __restrict__ qryf, const float* __restrict__ v,
    const int* __restrict__ lens, float* __restrict__ out)
{
    __shared__ float smem[14336];    // 56 KB

    const int bid = blockIdx.x;      // 0..255
    const int tid = threadIdx.x;
    const int b   = bid & 7;
    const int t0  = (bid >> 3) * 8;
    const int l = tid & 63;
    const int w = tid >> 6;          // 0..15

    float* qls = smem;               // [t][j] 8*512 floats
    float* pls = smem + 4096;        // [4][8][256] floats; aliased avred
    float* wls = smem + 12288;       // [8][256] floats

    {
        const float* qf = qryf + ((size_t)b * TD + t0) * HD;
        const int j = tid & 511;
        #pragma unroll
        for (int t = (tid >> 9); t < 8; t += 2)
            qls[t * 512 + j] = qf[t * HD + j];
    }
    __syncthreads();

    float a[8][4];
    #pragma unroll
    for (int t = 0; t < 8; ++t)
        #pragma unroll
        for (int c = 0; c < 4; ++c) a[t][c] = 0.0f;
    {
        const int jbase = w * 32;
        const float* ep = encT + (size_t)b * HD * SD + (size_t)jbase * SD + l * 4;
        #pragma unroll 4
        for (int jj = 0; jj < 32; ++jj) {
            float4 e = *(const float4*)(ep + (size_t)jj * SD);
            float vj = v[jbase + jj];
            float qv[8];
            #pragma unroll
            for (int t = 0; t < 8; ++t) qv[t] = qls[t * 512 + jbase + jj];
            float ev[4] = {e.x, e.y, e.z, e.w};
            #pragma unroll
            for (int t = 0; t < 8; ++t)
                #pragma unroll
                for (int c = 0; c < 4; ++c) {
                    float p = fmaf(ev[c], qv[t], 1.0f);
                    a[t][c] = fmaf(vj, RCP(p), a[t][c]);
                }
        }
    }
    if (w < 4) {
        #pragma unroll
        for (int t = 0; t < 8; ++t)
            *(float4*)&pls[(w * 8 + t) * 256 + l * 4] =
                make_float4(a[t][0], a[t][1], a[t][2], a[t][3]);
    }
    __syncthreads();
    if (w >= 4 && w < 8) {
        #pragma unroll
        for (int t = 0; t < 8; ++t) {
            float4 c4 = *(const float4*)&pls[((w - 4) * 8 + t) * 256 + l * 4];
            c4.x += a[t][0]; c4.y += a[t][1]; c4.z += a[t][2]; c4.w += a[t][3];
            *(float4*)&pls[((w - 4) * 8 + t) * 256 + l * 4] = c4;
        }
    }
    __syncthreads();
    if (w >= 8 && w < 12) {
        #pragma unroll
        for (int t = 0; t < 8; ++t) {
            float4 c4 = *(const float4*)&pls[((w - 8) * 8 + t) * 256 + l * 4];
            c4.x += a[t][0]; c4.y += a[t][1]; c4.z += a[t][2]; c4.w += a[t][3];
            *(float4*)&pls[((w - 8) * 8 + t) * 256 + l * 4] = c4;
        }
    }
    __syncthreads();
    if (w >= 12) {
        #pragma unroll
        for (int t = 0; t < 8; ++t) {
            float4 c4 = *(const float4*)&pls[((w - 12) * 8 + t) * 256 + l * 4];
            c4.x += a[t][0]; c4.y += a[t][1]; c4.z += a[t][2]; c4.w += a[t][3];
            *(float4*)&pls[((w - 12) * 8 + t) * 256 + l * 4] = c4;
        }
    }
    __syncthreads();

    if (w < 8) {
        const int t = w;
        float p[4] = {0, 0, 0, 0};
        #pragma unroll
        for (int g = 0; g < 4; ++g) {
            float4 pp = *(const float4*)&pls[(g * 8 + t) * 256 + l * 4];
            p[0] += pp.x; p[1] += pp.y; p[2] += pp.z; p[3] += pp.w;
        }
        const int len = lens[b];
        const int s0 = l * 4;
        float sc[4];
        #pragma unroll
        for (int c = 0; c < 4; ++c)
            sc[c] = (s0 + c < len) ? -2.0f * p[c] : -INFINITY;
        float mx = fmaxf(fmaxf(sc[0], sc[1]), fmaxf(sc[2], sc[3]));
        #pragma unroll
        for (int off = 32; off; off >>= 1) mx = fmaxf(mx, __shfl_xor(mx, off));
        float ex[4]; float sum = 0.0f;
        #pragma unroll
        for (int c = 0; c < 4; ++c) { ex[c] = __expf(sc[c] - mx); sum += ex[c]; }
        #pragma unroll
        for (int off = 32; off; off >>= 1) sum += __shfl_xor(sum, off);
        const float inv = RCP(sum);
        *(float4*)&wls[t * SD + s0] = make_float4(ex[0]*inv, ex[1]*inv, ex[2]*inv, ex[3]*inv);
    }
    __syncthreads();

    const int sg = tid >> 7;
    const int h4 = (tid & 127) * 4;
    float* avred = pls;
    float4 o[8];
    #pragma unroll
    for (int t = 0; t < 8; ++t) o[t] = make_float4(0.f, 0.f, 0.f, 0.f);
    {
        const float* eb = enc + (size_t)b * SD * HD + h4;
        #pragma unroll 2
        for (int ss = 0; ss < 32; ++ss) {
            const int s = sg * 32 + ss;
            float4 evv = *(const float4*)(eb + (size_t)s * HD);
            float wt[8];
            #pragma unroll
            for (int t = 0; t < 8; ++t) wt[t] = wls[t * SD + s];
            #pragma unroll
            for (int t = 0; t < 8; ++t) {
                o[t].x = fmaf(wt[t], evv.x, o[t].x);
                o[t].y = fmaf(wt[t], evv.y, o[t].y);
                o[t].z = fmaf(wt[t], evv.z, o[t].z);
                o[t].w = fmaf(wt[t], evv.w, o[t].w);
            }
        }
    }
    if (sg < 2) {
        #pragma unroll
        for (int t = 0; t < 8; ++t)
            *(float4*)&avred[(size_t)(sg * 8 + t) * 512 + h4] = o[t];
    }
    __syncthreads();
    if (sg >= 2 && sg < 4) {
        #pragma unroll
        for (int t = 0; t < 8; ++t) {
            float4 c4 = *(const float4*)&avred[(size_t)((sg - 2) * 8 + t) * 512 + h4];
            c4.x += o[t].x; c4.y += o[t].y; c4.z += o[t].z; c4.w += o[t].w;
            *(float4*)&avred[(size_t)((sg - 2) * 8 + t) * 512 + h4] = c4;
        }
    }
    __syncthreads();
    if (sg >= 4 && sg < 6) {
        #pragma unroll
        for (int t = 0; t < 8; ++t) {
            float4 c4 = *(const float4*)&avred[(size_t)((sg - 4) * 8 + t) * 512 + h4];
            c4.x += o[t].x; c4.y += o[t].y; c4.z += o[t].z; c4.w += o[t].w;
            *(float4*)&avred[(size_t)((sg - 4) * 8 + t) * 512 + h4] = c4;
        }
    }
    __syncthreads();
    if (sg >= 6) {
        #pragma unroll
        for (int t = 0; t < 8; ++t) {
            float4 c4 = *(const float4*)&avred[(size_t)((sg - 6) * 8 + t) * 512 + h4];
            c4.x += o[t].x; c4.y += o[t].y; c4.z += o[t].z; c4.w += o[t].w;
            *(float4*)&avred[(size_t)((sg - 6) * 8 + t) * 512 + h4] = c4;
        }
    }
    __syncthreads();

    {
        const int t  = tid >> 7;
        const int hh = (tid & 127) * 4;
        float4 x0 = *(const float4*)&avred[(size_t)(0 * 8 + t) * 512 + hh];
        float4 x1 = *(const float4*)&avred[(size_t)(1 * 8 + t) * 512 + hh];
        float4 r = make_float4(x0.x + x1.x, x0.y + x1.y, x0.z + x1.z, x0.w + x1.w);
        *(float4*)(out + ((size_t)b * TD + t0 + t) * HD + hh) = r;
    }
}

extern "C" void kernel_launch(void* const* d_in, const int* in_sizes, int n_in,
                              void* d_out, int out_size, void* d_ws, size_t ws_size,
                              hipStream_t stream) {
    const float* query = (const float*)d_in[0];
    const float* enc   = (const float*)d_in[1];
    const int*   lens  = (const int*)d_in[2];
    const float* W_h   = (const float*)d_in[3];
    const float* W_s   = (const float*)d_in[4];
    const float* v     = (const float*)d_in[5];
    float* out = (float*)d_out;

    char* ws = (char*)d_ws;
    float* encT = (float*)(ws);                       // 4 MB (B,H,S)  E_e
    float* qryf = (float*)(ws + ((size_t)4 << 20));   // 4 MB (B,T,H)  E_q

    // Plain launches only — graph-capture-safe (R7 lesson).
    projK<<<dim3(512), dim3(1024), 0, stream>>>(enc, query, W_h, W_s, encT, qryf);

    // Spill guard (R8 lesson): only the catastrophe gates.
    hipFuncAttributes fa{};
    bool use2 = (hipFuncGetAttributes(&fa, (const void*)attnK2) == hipSuccess) &&
                (fa.localSizeBytes == 0);

    if (use2) {
        // attnK + 8-deep score prefetch under the 128-VGPR budget.
        attnK2<<<dim3(256), dim3(1024), 0, stream>>>(enc, encT, qryf, v, lens, out);
    } else {
        // R7/R9-proven fused attn (bench 117.8 us).
        attnK<<<dim3(256), dim3(1024), 0, stream>>>(enc, encT, qryf, v, lens, out);
    }
}